// Round 2
// baseline (1325.515 us; speedup 1.0000x reference)
//
#include <hip/hip_runtime.h>

typedef __bf16 bf16;
typedef bf16 bf16x8 __attribute__((ext_vector_type(8)));
typedef float f32x4 __attribute__((ext_vector_type(4)));

#define NJ 33
#define FD 64
#define NB_TOT 32768
#define NROWS (NB_TOT*NJ)        // 1,081,344
#define NPAIRS (NROWS/32)        // 33,792 pairs of 16-row tiles
#define GRID 512
#define GWAVES (GRID*4)          // 2048 waves, ~16.5 pairs each

#define SELF4(j) ((unsigned)(j)*0x01010101u)

// neighbor ids packed 4x8bit, padded with self (weight forced to 0 past cnt)
__constant__ unsigned c_nbr[NJ] = {
  SELF4(0),SELF4(1),SELF4(2),SELF4(3),SELF4(4),SELF4(5),SELF4(6),SELF4(7),SELF4(8),SELF4(9),SELF4(10),
  (11u)|(12u<<8)|(23u<<16)|(13u<<24),
  (12u)|(11u<<8)|(24u<<16)|(14u<<24),
  (13u)|(11u<<8)|(15u<<16)|(13u<<24),
  (14u)|(12u<<8)|(16u<<16)|(14u<<24),
  (15u)|(13u<<8)|(15u<<16)|(15u<<24),
  (16u)|(14u<<8)|(16u<<16)|(16u<<24),
  SELF4(17),SELF4(18),SELF4(19),SELF4(20),SELF4(21),SELF4(22),
  (23u)|(11u<<8)|(24u<<16)|(25u<<24),
  (24u)|(12u<<8)|(23u<<16)|(26u<<24),
  (25u)|(23u<<8)|(27u<<16)|(25u<<24),
  (26u)|(24u<<8)|(28u<<16)|(26u<<24),
  (27u)|(25u<<8)|(27u<<16)|(27u<<24),
  (28u)|(26u<<8)|(28u<<16)|(28u<<24),
  SELF4(29),SELF4(30),SELF4(31),SELF4(32)
};
__constant__ int c_cnt[NJ] = {1,1,1,1,1,1,1,1,1,1,1,4,4,3,3,2,2,1,1,1,1,1,1,4,4,3,3,2,2,1,1,1,1};
__constant__ float c_winv[NJ] = {1.f,1.f,1.f,1.f,1.f,1.f,1.f,1.f,1.f,1.f,1.f,
  0.25f,0.25f,0.33333334f,0.33333334f,0.5f,0.5f,
  1.f,1.f,1.f,1.f,1.f,1.f,
  0.25f,0.25f,0.33333334f,0.33333334f,0.5f,0.5f,
  1.f,1.f,1.f,1.f};

#define MFMA(a,b,c) __builtin_amdgcn_mfma_f32_16x16x32_bf16((a),(b),(c),0,0,0)

__device__ static inline f32x4 splat4(float x){ f32x4 v = {x,x,x,x}; return v; }
__device__ static inline float fast_sigmoid(float x){
  return __builtin_amdgcn_rcpf(1.f + __expf(-x));
}
__device__ static inline float fast_tanh(float x){
  return 1.f - 2.f*__builtin_amdgcn_rcpf(1.f + __expf(2.f*x));
}

// LDS weight layout: rows 0..63 = msg_w, 64..255 = w_ih, 256..447 = w_hh (bf16).
// Each 64-elem row stored as 8 groups of 8 bf16, group g placed at g ^ (row&7)
// (XOR swizzle -> ~conflict-free B-fragment ds_read_b128).
__global__ __launch_bounds__(256, 2)
void skeleton_gnn(const float* __restrict__ feats, const float* __restrict__ vis,
                  const float* __restrict__ msgw, const float* __restrict__ msgb,
                  const float* __restrict__ wih,  const float* __restrict__ whh,
                  const float* __restrict__ bih,  const float* __restrict__ bhh,
                  float* __restrict__ out)
{
  __shared__ __align__(16) bf16 wlds[448*FD];        // 57,344 B
  __shared__ __align__(16) bf16 scr[4][16*72];       // per-wave msgs C->A tile, 9,216 B

  const int tid  = threadIdx.x;
  const int wid  = tid >> 6;
  const int lane = tid & 63;
  const int m16  = lane & 15;
  const int quad = lane >> 4;

  // ---- stage weights into LDS (fp32 -> bf16, swizzled), coalesced 32B/thread
  for (int g = tid; g < 448*8; g += 256) {
    const int e = g >> 3, gr = g & 7;
    const float* src = (e < 64) ? (msgw + e*FD)
                     : (e < 256) ? (wih + (e-64)*FD)
                     : (whh + (e-256)*FD);
    const f32x4 v0 = *(const f32x4*)(src + gr*8);
    const f32x4 v1 = *(const f32x4*)(src + gr*8 + 4);
    bf16x8 v;
#pragma unroll
    for (int e2 = 0; e2 < 4; ++e2) { v[e2] = (bf16)v0[e2]; v[4+e2] = (bf16)v1[e2]; }
    *(bf16x8*)(wlds + e*FD + ((gr ^ (e & 7)) << 3)) = v;
  }

  // ---- per-lane bias registers (col = ct*16 + m16 in C-layout)
  float bias_rz[8], bias_in[4], bias_hn[4], bias_m[4];
#pragma unroll
  for (int ct = 0; ct < 8; ++ct)
    bias_rz[ct] = bih[ct*16+m16] + bhh[ct*16+m16];
#pragma unroll
  for (int ct = 0; ct < 4; ++ct) {
    const int c = 128 + ct*16 + m16;
    bias_in[ct] = bih[c];
    bias_hn[ct] = bhh[c];
    bias_m[ct]  = msgb[ct*16+m16];
  }
  __syncthreads();

  bf16* smsg = &scr[wid][0];      // msgs C-layout -> A-layout round-trip tile

  for (int p = blockIdx.x*4 + wid; p < NPAIRS; p += GWAVES) {
    const int r0 = p*32;
    bf16x8 a_h[2][2], a_m[2][2], a_g[2][2];

    // ---- neighbor aggregation -> A-fragments (agg) + self row -> A-fragments (h)
#pragma unroll
    for (int s = 0; s < 2; ++s) {
      const int r = r0 + s*16 + m16;
      const int b = r / NJ;
      const int j = r - b*NJ;
      const unsigned nb = c_nbr[j];
      const float icw = c_winv[j];
      const int cnt = c_cnt[j];
      const float* fb = feats + (size_t)b*(NJ*FD);
      const float* vb = vis + b*NJ;
      int noff[4]; float wv[4];
#pragma unroll
      for (int nn = 0; nn < 4; ++nn) {
        const int n = (nb >> (8*nn)) & 255;
        noff[nn] = n*FD;
        const float w = vb[n] * icw;
        wv[nn] = (nn < cnt) ? w : 0.f;
      }
#pragma unroll
      for (int t = 0; t < 2; ++t) {
        const int k0 = t*32 + quad*8;
        const f32x4 s0 = *(const f32x4*)(fb + noff[0] + k0);       // self row
        const f32x4 s1 = *(const f32x4*)(fb + noff[0] + k0 + 4);
        bf16x8 ah;
        float acc[8];
#pragma unroll
        for (int e = 0; e < 4; ++e) {
          ah[e] = (bf16)s0[e];   acc[e]   = wv[0]*s0[e];
          ah[4+e] = (bf16)s1[e]; acc[4+e] = wv[0]*s1[e];
        }
        a_h[s][t] = ah;
#pragma unroll
        for (int nn = 1; nn < 4; ++nn) {
          const f32x4 v0 = *(const f32x4*)(fb + noff[nn] + k0);
          const f32x4 v1 = *(const f32x4*)(fb + noff[nn] + k0 + 4);
#pragma unroll
          for (int e = 0; e < 4; ++e) {
            acc[e]   += wv[nn]*v0[e];
            acc[4+e] += wv[nn]*v1[e];
          }
        }
        bf16x8 am;
#pragma unroll
        for (int e = 0; e < 8; ++e) am[e] = (bf16)acc[e];
        a_m[s][t] = am;
      }
    }

    // ---- msgs = agg @ msg_w^T + msg_b  (B-fragments shared across both 16-row tiles)
    f32x4 mc[2][4];
#pragma unroll
    for (int ct = 0; ct < 4; ++ct) { mc[0][ct] = splat4(bias_m[ct]); mc[1][ct] = splat4(bias_m[ct]); }
#pragma unroll
    for (int ct = 0; ct < 4; ++ct) {
      const int e = ct*16 + m16;
#pragma unroll
      for (int t = 0; t < 2; ++t) {
        const int g = t*4 + quad;
        const bf16x8 bw = *(const bf16x8*)(wlds + e*FD + ((g ^ (e & 7)) << 3));
        mc[0][ct] = MFMA(a_m[0][t], bw, mc[0][ct]);
        mc[1][ct] = MFMA(a_m[1][t], bw, mc[1][ct]);
      }
    }
    // C-layout -> A-layout via per-wave LDS tile (wave-private, in-order ds ops)
#pragma unroll
    for (int s = 0; s < 2; ++s) {
#pragma unroll
      for (int ct = 0; ct < 4; ++ct)
#pragma unroll
        for (int rg = 0; rg < 4; ++rg)
          smsg[(quad*4+rg)*72 + ct*16 + m16] = (bf16)mc[s][ct][rg];
#pragma unroll
      for (int t = 0; t < 2; ++t)
        a_g[s][t] = *(const bf16x8*)(smsg + m16*72 + t*32 + quad*8);
    }

    // ---- gi/gh GEMMs: r,z parts accumulate ih+hh into one acc; n parts kept split
    f32x4 arz[2][8], ain[2][4], ahn[2][4];
#pragma unroll
    for (int ct = 0; ct < 8; ++ct) { arz[0][ct] = splat4(bias_rz[ct]); arz[1][ct] = splat4(bias_rz[ct]); }
#pragma unroll
    for (int ct = 0; ct < 4; ++ct) {
      ain[0][ct] = splat4(bias_in[ct]); ain[1][ct] = splat4(bias_in[ct]);
      ahn[0][ct] = splat4(bias_hn[ct]); ahn[1][ct] = splat4(bias_hn[ct]);
    }
#pragma unroll
    for (int ct = 0; ct < 8; ++ct) {
      const int e1 = 64  + ct*16 + m16;   // w_ih rows 0..127  (r,z)
      const int e2 = 256 + ct*16 + m16;   // w_hh rows 0..127  (r,z)
#pragma unroll
      for (int t = 0; t < 2; ++t) {
        const int g = t*4 + quad;
        const bf16x8 b1 = *(const bf16x8*)(wlds + e1*FD + ((g ^ (e1 & 7)) << 3));
        arz[0][ct] = MFMA(a_g[0][t], b1, arz[0][ct]);
        arz[1][ct] = MFMA(a_g[1][t], b1, arz[1][ct]);
        const bf16x8 b2 = *(const bf16x8*)(wlds + e2*FD + ((g ^ (e2 & 7)) << 3));
        arz[0][ct] = MFMA(a_h[0][t], b2, arz[0][ct]);
        arz[1][ct] = MFMA(a_h[1][t], b2, arz[1][ct]);
      }
    }
#pragma unroll
    for (int ct = 0; ct < 4; ++ct) {
      const int e1 = 192 + ct*16 + m16;   // w_ih rows 128..191 (n)
      const int e2 = 384 + ct*16 + m16;   // w_hh rows 128..191 (n)
#pragma unroll
      for (int t = 0; t < 2; ++t) {
        const int g = t*4 + quad;
        const bf16x8 b1 = *(const bf16x8*)(wlds + e1*FD + ((g ^ (e1 & 7)) << 3));
        ain[0][ct] = MFMA(a_g[0][t], b1, ain[0][ct]);
        ain[1][ct] = MFMA(a_g[1][t], b1, ain[1][ct]);
        const bf16x8 b2 = *(const bf16x8*)(wlds + e2*FD + ((g ^ (e2 & 7)) << 3));
        ahn[0][ct] = MFMA(a_h[0][t], b2, ahn[0][ct]);
        ahn[1][ct] = MFMA(a_h[1][t], b2, ahn[1][ct]);
      }
    }

    // ---- GRU gates in C-layout; h reloaded fp32 from global (L1/L2 hit);
    //      fp32 stores directly at C-layout coords (16-lane x 4B = 64B segments)
#pragma unroll
    for (int s = 0; s < 2; ++s) {
      const size_t rowbase = (size_t)(r0 + s*16)*FD;
      float hv[4][4];
#pragma unroll
      for (int ct = 0; ct < 4; ++ct)
#pragma unroll
        for (int rg = 0; rg < 4; ++rg)
          hv[ct][rg] = feats[rowbase + (size_t)(quad*4+rg)*FD + ct*16 + m16];
#pragma unroll
      for (int ct = 0; ct < 4; ++ct) {
#pragma unroll
        for (int rg = 0; rg < 4; ++rg) {
          const float rr = fast_sigmoid(arz[s][ct][rg]);
          const float zz = fast_sigmoid(arz[s][ct+4][rg]);
          const float nv = fast_tanh(ain[s][ct][rg] + rr*ahn[s][ct][rg]);
          const float o  = nv + zz*(hv[ct][rg] - nv);     // == (1-z)*n + z*h
          out[rowbase + (size_t)(quad*4+rg)*FD + ct*16 + m16] = o;
        }
      }
    }
  }
}

extern "C" void kernel_launch(void* const* d_in, const int* in_sizes, int n_in,
                              void* d_out, int out_size, void* d_ws, size_t ws_size,
                              hipStream_t stream) {
  (void)in_sizes; (void)n_in; (void)d_ws; (void)ws_size; (void)out_size;
  const float* feats = (const float*)d_in[0];
  const float* vis   = (const float*)d_in[1];
  const float* msgw  = (const float*)d_in[2];
  const float* msgb  = (const float*)d_in[3];
  const float* wih   = (const float*)d_in[4];
  const float* whh   = (const float*)d_in[5];
  const float* bih   = (const float*)d_in[6];
  const float* bhh   = (const float*)d_in[7];
  skeleton_gnn<<<GRID, 256, 0, stream>>>(feats, vis, msgw, msgb, wih, whh, bih, bhh, (float*)d_out);
}